// Round 8
// baseline (403.193 us; speedup 1.0000x reference)
//
#include <hip/hip_runtime.h>

typedef __bf16 bf16_t;
typedef __bf16 bf16x4 __attribute__((ext_vector_type(4)));
typedef __bf16 bf16x8 __attribute__((ext_vector_type(8)));
typedef float f32x4 __attribute__((ext_vector_type(4)));

#define SCALE_LOG2E 0.25510803519787995f  // 32^-0.5 * log2(e)
#define LOG2E 1.4426950408889634f
#define SWZ(row) (((row) & 15) << 4)

__device__ __forceinline__ f32x4 mk4(float4 v) { return (f32x4){v.x, v.y, v.z, v.w}; }
__device__ __forceinline__ bf16x8 pack2(f32x4 a, f32x4 b) {
  bf16x4 lo = __builtin_convertvector(a, bf16x4);
  bf16x4 hi = __builtin_convertvector(b, bf16x4);
  return __builtin_shufflevector(lo, hi, 0, 1, 2, 3, 4, 5, 6, 7);
}

// ---- prep 1: transposed bf16 weights; Q/K head-rows permuted, Q pre-scaled ----
__global__ __launch_bounds__(256, 1) void prep_weights(
    const float* __restrict__ wqkv, const float* __restrict__ wout,
    bf16_t* __restrict__ wqkvT, bf16_t* __restrict__ woutT) {
  int i = blockIdx.x * 256 + threadIdx.x;   // 1024*256
  int n = i >> 8, k = i & 255;
  if (n < 768) {
    int s = n >> 8, hl = n & 255;
    int src;
    if (s < 2) {
      int h = hl >> 5, w = hl & 31, c = (w >> 4) & 1, r = w & 15;
      src = 32 * h + 8 * (r >> 2) + 4 * c + (r & 3);
    } else {
      src = hl;
    }
    float v = wqkv[k * 768 + s * 256 + src];
    if (s == 0) v *= SCALE_LOG2E;
    wqkvT[n * 256 + k] = (bf16_t)v;
  } else {
    int m = n - 768;
    woutT[m * 256 + k] = (bf16_t)wout[k * 256 + m];
  }
}

// ---- prep 2: rel-pos bias, interleaved fragment order, log2e-scaled ----
__global__ __launch_bounds__(256, 1) void prep_bias(
    const float* __restrict__ pos_enc, bf16_t* __restrict__ biasI) {
  int i = blockIdx.x * 256 + threadIdx.x;   // 8*4*4*64*4 = 32768
  int ii = i & 3, lane = (i >> 2) & 63, nt = (i >> 8) & 3, qt = (i >> 10) & 3, h = i >> 12;
  int g = lane >> 4, cc = lane & 15;
  int q = 32 * (qt >> 1) + 4 * (qt & 1) + 8 * (cc >> 2) + (cc & 3);
  int key = 32 * (nt >> 1) + 4 * (nt & 1) + 8 * g + ii;
  int qy = q >> 3, qx = q & 7, ky = key >> 3, kx = key & 7;
  biasI[i] = (bf16_t)(pos_enc[h * 225 + (qy - ky + 7) * 15 + (qx - kx + 7)] * LOG2E);
}

// LDS 32768 B, single region: X bf16 [64 tok][512B ch] -> O overlay after barrier.
// 256 threads = 4 waves, wave w owns heads 2w,2w+1. Target 3 blocks/CU (12 waves).
__global__ __launch_bounds__(256, 3) void swin_attn(
    const float* __restrict__ x,
    const float* __restrict__ b_qkv,
    const float* __restrict__ b_out,
    const bf16_t* __restrict__ wqkvT,
    const bf16_t* __restrict__ woutT,
    const bf16_t* __restrict__ biasI,
    float* __restrict__ out) {
  __shared__ __attribute__((aligned(16))) char smem[32768];

  const int tid  = threadIdx.x;
  const int wid  = blockIdx.x;
  const int bb   = wid >> 6;
  const int w64  = wid & 63;
  const int wy   = w64 >> 3, wx = w64 & 7;
  const int wave = tid >> 6, lane = tid & 63;
  const int g    = lane >> 4, cc = lane & 15;
  const bool maskY = (wy == 7), maskX = (wx == 7);
  const int rb = 8 * (cc >> 2) + (cc & 3);   // interleaved row base per lane

  // ---------------- phase 0: shifted-window gather -> X (bf16) ----------------
  {
    const float* xb = x + (size_t)bb * 4096 * 256;
    #pragma unroll
    for (int it = 0; it < 16; ++it) {
      int fi = tid + 256 * it;
      int r = fi >> 6, c4 = fi & 63;
      int hh = (8 * wy + (r >> 3) + 4) & 63;
      int ww = (8 * wx + (r & 7) + 4) & 63;
      const float4 v = ((const float4*)(xb + ((size_t)hh * 64 + ww) * 256))[c4];
      bf16x4 pk = __builtin_convertvector(mk4(v), bf16x4);
      *(bf16x4*)(smem + r * 512 + ((8 * c4) ^ SWZ(r))) = pk;
    }
  }
  __syncthreads();

  // ---- QKV for head h (QK pass then V pass; outputs are MFMA fragments) ----
  auto qkv = [&](int h, bf16x8 qp[4], bf16x8 kp[4], bf16x8 vp[2][2]) {
    {
      f32x4 aq[2][4], ak[2][4];
      #pragma unroll
      for (int c = 0; c < 2; ++c)
        #pragma unroll
        for (int t = 0; t < 4; ++t) {
          aq[c][t] = (f32x4){0.f, 0.f, 0.f, 0.f};
          ak[c][t] = (f32x4){0.f, 0.f, 0.f, 0.f};
        }
      const bf16_t* wq = wqkvT + (size_t)(32 * h) * 256;
      const bf16_t* wk = wqkvT + (size_t)(256 + 32 * h) * 256;
      #pragma unroll
      for (int ks = 0; ks < 8; ++ks) {
        bf16x8 aks[4];
        #pragma unroll
        for (int t = 0; t < 4; ++t) {
          int row = 32 * (t >> 1) + 4 * (t & 1) + rb;
          aks[t] = *(const bf16x8*)(smem + row * 512 + ((64 * ks + 16 * g) ^ SWZ(row)));
        }
        #pragma unroll
        for (int c = 0; c < 2; ++c) {
          int ro = (16 * c + cc) * 256 + 32 * ks + 8 * g;
          bf16x8 fq = *(const bf16x8*)&wq[ro];
          bf16x8 fk = *(const bf16x8*)&wk[ro];
          #pragma unroll
          for (int t = 0; t < 4; ++t) {
            aq[c][t] = __builtin_amdgcn_mfma_f32_16x16x32_bf16(fq, aks[t], aq[c][t], 0, 0, 0);
            ak[c][t] = __builtin_amdgcn_mfma_f32_16x16x32_bf16(fk, aks[t], ak[c][t], 0, 0, 0);
          }
        }
      }
      f32x4 bq0 = mk4(*(const float4*)&b_qkv[32 * h + 8 * g]) * SCALE_LOG2E;
      f32x4 bq1 = mk4(*(const float4*)&b_qkv[32 * h + 8 * g + 4]) * SCALE_LOG2E;
      f32x4 bk0 = mk4(*(const float4*)&b_qkv[256 + 32 * h + 8 * g]);
      f32x4 bk1 = mk4(*(const float4*)&b_qkv[256 + 32 * h + 8 * g + 4]);
      #pragma unroll
      for (int t = 0; t < 4; ++t) {
        qp[t] = pack2(aq[0][t] + bq0, aq[1][t] + bq1);
        kp[t] = pack2(ak[0][t] + bk0, ak[1][t] + bk1);
      }
    }
    {
      f32x4 av[4][2];
      #pragma unroll
      for (int t = 0; t < 4; ++t)
        #pragma unroll
        for (int c = 0; c < 2; ++c) av[t][c] = (f32x4){0.f, 0.f, 0.f, 0.f};
      const bf16_t* wv = wqkvT + (size_t)(512 + 32 * h) * 256;
      #pragma unroll
      for (int ks = 0; ks < 8; ++ks) {
        bf16x8 aks[4];
        #pragma unroll
        for (int t = 0; t < 4; ++t) {
          int row = 32 * (t >> 1) + 4 * (t & 1) + rb;
          aks[t] = *(const bf16x8*)(smem + row * 512 + ((64 * ks + 16 * g) ^ SWZ(row)));
        }
        #pragma unroll
        for (int c = 0; c < 2; ++c) {
          bf16x8 fv = *(const bf16x8*)&wv[(16 * c + cc) * 256 + 32 * ks + 8 * g];
          #pragma unroll
          for (int t = 0; t < 4; ++t)
            av[t][c] = __builtin_amdgcn_mfma_f32_16x16x32_bf16(aks[t], fv, av[t][c], 0, 0, 0);
        }
      }
      #pragma unroll
      for (int c = 0; c < 2; ++c) {
        float bv = b_qkv[512 + 32 * h + 16 * c + cc];
        f32x4 bv4 = (f32x4){bv, bv, bv, bv};
        #pragma unroll
        for (int ks = 0; ks < 2; ++ks)
          vp[c][ks] = pack2(av[2 * ks][c] + bv4, av[2 * ks + 1][c] + bv4);
      }
    }
  };

  // ---- attention head h: per-qt fused softmax+PV (low register peak) ----
  auto attn = [&](int h, const bf16x8 qp[4], const bf16x8 kp[4],
                  const bf16x8 vp[2][2], bf16x4 ob[2][4]) {
    const bf16_t* bI = biasI + h * 4096 + lane * 4;
    #pragma unroll
    for (int qt = 0; qt < 4; ++qt) {
      f32x4 sv[4];
      #pragma unroll
      for (int nt = 0; nt < 4; ++nt)
        sv[nt] = __builtin_amdgcn_mfma_f32_16x16x32_bf16(
            kp[nt], qp[qt], (f32x4){0.f, 0.f, 0.f, 0.f}, 0, 0, 0);
      #pragma unroll
      for (int nt = 0; nt < 4; ++nt) {
        bool dead = (maskY && ((qt < 2) != (nt < 2))) || (maskX && ((qt & 1) != (nt & 1)));
        if (dead) {
          sv[nt] = (f32x4){-3.0e38f, -3.0e38f, -3.0e38f, -3.0e38f};
        } else {
          bf16x4 bb4 = *(const bf16x4*)&bI[(qt * 4 + nt) * 256];
          sv[nt] = sv[nt] + __builtin_convertvector(bb4, f32x4);
        }
      }
      float mx = -3.0e38f;
      #pragma unroll
      for (int nt = 0; nt < 4; ++nt)
        #pragma unroll
        for (int i = 0; i < 4; ++i) mx = fmaxf(mx, sv[nt][i]);
      mx = fmaxf(mx, __shfl_xor(mx, 16));
      mx = fmaxf(mx, __shfl_xor(mx, 32));
      float sum = 0.f;
      #pragma unroll
      for (int nt = 0; nt < 4; ++nt)
        #pragma unroll
        for (int i = 0; i < 4; ++i) {
          float e = exp2f(sv[nt][i] - mx);
          sv[nt][i] = e;
          sum += e;
        }
      sum += __shfl_xor(sum, 16);
      sum += __shfl_xor(sum, 32);
      float rinv = 1.0f / sum;
      #pragma unroll
      for (int nt = 0; nt < 4; ++nt) sv[nt] *= rinv;
      bf16x8 p0 = pack2(sv[0], sv[1]);
      bf16x8 p1 = pack2(sv[2], sv[3]);
      #pragma unroll
      for (int c = 0; c < 2; ++c) {
        f32x4 oa = __builtin_amdgcn_mfma_f32_16x16x32_bf16(
            vp[c][0], p0, (f32x4){0.f, 0.f, 0.f, 0.f}, 0, 0, 0);
        oa = __builtin_amdgcn_mfma_f32_16x16x32_bf16(vp[c][1], p1, oa, 0, 0, 0);
        ob[c][qt] = __builtin_convertvector(oa, bf16x4);
      }
    }
  };

  // ---- packed O tiles -> X-overlay; head h owns channels 32h..32h+31 ----
  auto writeO = [&](int h, const bf16x4 ob[2][4]) {
    #pragma unroll
    for (int c = 0; c < 2; ++c)
      #pragma unroll
      for (int qt = 0; qt < 4; ++qt) {
        int tok = 32 * (qt >> 1) + 4 * (qt & 1) + rb;
        *(bf16x4*)(smem + tok * 512 + ((2 * (32 * h + 16 * c + 4 * g)) ^ SWZ(tok))) = ob[c][qt];
      }
  };

  {
    bf16x8 qp[4], kp[4], vp[2][2];
    bf16x4 ob0[2][4], ob1[2][4];
    const int h0 = 2 * wave, h1 = 2 * wave + 1;
    qkv(h0, qp, kp, vp);
    attn(h0, qp, kp, vp, ob0);
    qkv(h1, qp, kp, vp);
    __syncthreads();            // all X reads complete -> O may overlay X
    writeO(h0, ob0);
    attn(h1, qp, kp, vp, ob1);
    writeO(h1, ob1);
  }
  __syncthreads();              // O complete

  // ---- out projection D = W_out·O^T + reverse-shift scatter ----
  {
    f32x4 pacc[4][4];  // wave owns 64 output channels: [c2][t]
    #pragma unroll
    for (int c = 0; c < 4; ++c)
      #pragma unroll
      for (int t = 0; t < 4; ++t) pacc[c][t] = (f32x4){0.f, 0.f, 0.f, 0.f};
    #pragma unroll
    for (int ks = 0; ks < 8; ++ks) {
      bf16x8 of[4];
      #pragma unroll
      for (int t = 0; t < 4; ++t) {
        int row = 16 * t + cc;
        of[t] = *(const bf16x8*)(smem + row * 512 + ((64 * ks + 16 * g) ^ SWZ(row)));
      }
      #pragma unroll
      for (int c2 = 0; c2 < 4; ++c2) {
        bf16x8 wf = *(const bf16x8*)&woutT[(size_t)(64 * wave + 16 * c2 + cc) * 256 + 32 * ks + 8 * g];
        #pragma unroll
        for (int t = 0; t < 4; ++t)
          pacc[c2][t] = __builtin_amdgcn_mfma_f32_16x16x32_bf16(wf, of[t], pacc[c2][t], 0, 0, 0);
      }
    }
    #pragma unroll
    for (int c2 = 0; c2 < 4; ++c2) {
      int ch = 64 * wave + 16 * c2 + 4 * g;
      float4 bo4 = *(const float4*)&b_out[ch];
      #pragma unroll
      for (int t = 0; t < 4; ++t) {
        int q = 16 * t + cc;
        int hh2 = (8 * wy + (q >> 3) + 4) & 63;
        int ww2 = (8 * wx + (q & 7) + 4) & 63;
        float4 st;
        st.x = pacc[c2][t][0] + bo4.x;
        st.y = pacc[c2][t][1] + bo4.y;
        st.z = pacc[c2][t][2] + bo4.z;
        st.w = pacc[c2][t][3] + bo4.w;
        *(float4*)&out[(((size_t)bb * 4096) + hh2 * 64 + ww2) * 256 + ch] = st;
      }
    }
  }
}

extern "C" void kernel_launch(void* const* d_in, const int* in_sizes, int n_in,
                              void* d_out, int out_size, void* d_ws, size_t ws_size,
                              hipStream_t stream) {
  const float* x       = (const float*)d_in[0];
  const float* w_qkv   = (const float*)d_in[1];
  const float* b_qkv   = (const float*)d_in[2];
  const float* w_out   = (const float*)d_in[3];
  const float* b_out   = (const float*)d_in[4];
  const float* pos_enc = (const float*)d_in[5];
  float* out = (float*)d_out;

  bf16_t* wqkvT = (bf16_t*)d_ws;          // 768*256
  bf16_t* woutT = wqkvT + 768 * 256;      // 256*256
  bf16_t* biasI = woutT + 256 * 256;      // 32768

  prep_weights<<<dim3(1024), dim3(256), 0, stream>>>(w_qkv, w_out, wqkvT, woutT);
  prep_bias<<<dim3(128), dim3(256), 0, stream>>>(pos_enc, biasI);
  swin_attn<<<dim3(2048), dim3(256), 0, stream>>>(
      x, b_qkv, b_out, wqkvT, woutT, biasI, out);
}

// Round 9
// 362.716 us; speedup vs baseline: 1.1116x; 1.1116x over previous
//
#include <hip/hip_runtime.h>

typedef __bf16 bf16_t;
typedef __bf16 bf16x4 __attribute__((ext_vector_type(4)));
typedef __bf16 bf16x8 __attribute__((ext_vector_type(8)));
typedef float f32x4 __attribute__((ext_vector_type(4)));

#define SCALE_LOG2E 0.25510803519787995f  // 32^-0.5 * log2(e)
#define LOG2E 1.4426950408889634f
#define SWZ(row) (((row) & 15) << 4)
#define SLAB_OFF 32768
#define SLAB_STRIDE 5120   // per even-head slab: 64 tok x 80 B

__device__ __forceinline__ f32x4 mk4(float4 v) { return (f32x4){v.x, v.y, v.z, v.w}; }
__device__ __forceinline__ bf16x8 pack2(f32x4 a, f32x4 b) {
  bf16x4 lo = __builtin_convertvector(a, bf16x4);
  bf16x4 hi = __builtin_convertvector(b, bf16x4);
  return __builtin_shufflevector(lo, hi, 0, 1, 2, 3, 4, 5, 6, 7);
}

// ---- prep 1: transposed bf16 weights; Q/K head-rows permuted, Q pre-scaled ----
__global__ __launch_bounds__(256, 1) void prep_weights(
    const float* __restrict__ wqkv, const float* __restrict__ wout,
    bf16_t* __restrict__ wqkvT, bf16_t* __restrict__ woutT) {
  int i = blockIdx.x * 256 + threadIdx.x;   // 1024*256
  int n = i >> 8, k = i & 255;
  if (n < 768) {
    int s = n >> 8, hl = n & 255;
    int src;
    if (s < 2) {
      int h = hl >> 5, w = hl & 31, c = (w >> 4) & 1, r = w & 15;
      src = 32 * h + 8 * (r >> 2) + 4 * c + (r & 3);
    } else {
      src = hl;
    }
    float v = wqkv[k * 768 + s * 256 + src];
    if (s == 0) v *= SCALE_LOG2E;
    wqkvT[n * 256 + k] = (bf16_t)v;
  } else {
    int m = n - 768;
    woutT[m * 256 + k] = (bf16_t)wout[k * 256 + m];
  }
}

// ---- prep 2: rel-pos bias, interleaved fragment order, log2e-scaled ----
__global__ __launch_bounds__(256, 1) void prep_bias(
    const float* __restrict__ pos_enc, bf16_t* __restrict__ biasI) {
  int i = blockIdx.x * 256 + threadIdx.x;   // 8*4*4*64*4 = 32768
  int ii = i & 3, lane = (i >> 2) & 63, nt = (i >> 8) & 3, qt = (i >> 10) & 3, h = i >> 12;
  int g = lane >> 4, cc = lane & 15;
  int q = 32 * (qt >> 1) + 4 * (qt & 1) + 8 * (cc >> 2) + (cc & 3);
  int key = 32 * (nt >> 1) + 4 * (nt & 1) + 8 * g + ii;
  int qy = q >> 3, qx = q & 7, ky = key >> 3, kx = key & 7;
  biasI[i] = (bf16_t)(pos_enc[h * 225 + (qy - ky + 7) * 15 + (qx - kx + 7)] * LOG2E);
}

// LDS 53248 B (3 blocks/CU):
//  [0, 32768): X bf16 [64 tok][512B ch] swz  -> odd-head O overlay after bar2
//  [32768, 53248): even-head O slabs: slab w (head 2w): [64 tok][80B], chl bytes [0,64)
// 256 threads = 4 waves, wave w owns heads 2w (even) and 2w+1 (odd).
__global__ __launch_bounds__(256, 3) void swin_attn(
    const float* __restrict__ x,
    const float* __restrict__ b_qkv,
    const float* __restrict__ b_out,
    const bf16_t* __restrict__ wqkvT,
    const bf16_t* __restrict__ woutT,
    const bf16_t* __restrict__ biasI,
    float* __restrict__ out) {
  __shared__ __attribute__((aligned(16))) char smem[53248];

  const int tid  = threadIdx.x;
  const int wid  = blockIdx.x;
  const int bb   = wid >> 6;
  const int w64  = wid & 63;
  const int wy   = w64 >> 3, wx = w64 & 7;
  const int wave = tid >> 6, lane = tid & 63;
  const int g    = lane >> 4, cc = lane & 15;
  const bool maskY = (wy == 7), maskX = (wx == 7);
  const int rb = 8 * (cc >> 2) + (cc & 3);   // interleaved row base per lane

  // ---------------- phase 0: shifted-window gather -> X (bf16) ----------------
  {
    const float* xb = x + (size_t)bb * 4096 * 256;
    #pragma unroll
    for (int it = 0; it < 16; ++it) {
      int fi = tid + 256 * it;
      int r = fi >> 6, c4 = fi & 63;
      int hh = (8 * wy + (r >> 3) + 4) & 63;
      int ww = (8 * wx + (r & 7) + 4) & 63;
      const float4 v = ((const float4*)(xb + ((size_t)hh * 64 + ww) * 256))[c4];
      bf16x4 pk = __builtin_convertvector(mk4(v), bf16x4);
      *(bf16x4*)(smem + r * 512 + ((8 * c4) ^ SWZ(r))) = pk;
    }
  }
  __syncthreads();

  // ---- QKV for head h (QK pass then V pass; outputs are MFMA fragments) ----
  auto qkv = [&](int h, bf16x8 qp[4], bf16x8 kp[4], bf16x8 vp[2][2]) {
    {
      f32x4 aq[2][4], ak[2][4];
      #pragma unroll
      for (int c = 0; c < 2; ++c)
        #pragma unroll
        for (int t = 0; t < 4; ++t) {
          aq[c][t] = (f32x4){0.f, 0.f, 0.f, 0.f};
          ak[c][t] = (f32x4){0.f, 0.f, 0.f, 0.f};
        }
      const bf16_t* wq = wqkvT + (size_t)(32 * h) * 256;
      const bf16_t* wk = wqkvT + (size_t)(256 + 32 * h) * 256;
      #pragma unroll
      for (int ks = 0; ks < 8; ++ks) {
        bf16x8 aks[4];
        #pragma unroll
        for (int t = 0; t < 4; ++t) {
          int row = 32 * (t >> 1) + 4 * (t & 1) + rb;
          aks[t] = *(const bf16x8*)(smem + row * 512 + ((64 * ks + 16 * g) ^ SWZ(row)));
        }
        #pragma unroll
        for (int c = 0; c < 2; ++c) {
          int ro = (16 * c + cc) * 256 + 32 * ks + 8 * g;
          bf16x8 fq = *(const bf16x8*)&wq[ro];
          bf16x8 fk = *(const bf16x8*)&wk[ro];
          #pragma unroll
          for (int t = 0; t < 4; ++t) {
            aq[c][t] = __builtin_amdgcn_mfma_f32_16x16x32_bf16(fq, aks[t], aq[c][t], 0, 0, 0);
            ak[c][t] = __builtin_amdgcn_mfma_f32_16x16x32_bf16(fk, aks[t], ak[c][t], 0, 0, 0);
          }
        }
      }
      f32x4 bq0 = mk4(*(const float4*)&b_qkv[32 * h + 8 * g]) * SCALE_LOG2E;
      f32x4 bq1 = mk4(*(const float4*)&b_qkv[32 * h + 8 * g + 4]) * SCALE_LOG2E;
      f32x4 bk0 = mk4(*(const float4*)&b_qkv[256 + 32 * h + 8 * g]);
      f32x4 bk1 = mk4(*(const float4*)&b_qkv[256 + 32 * h + 8 * g + 4]);
      #pragma unroll
      for (int t = 0; t < 4; ++t) {
        qp[t] = pack2(aq[0][t] + bq0, aq[1][t] + bq1);
        kp[t] = pack2(ak[0][t] + bk0, ak[1][t] + bk1);
      }
    }
    {
      f32x4 av[4][2];
      #pragma unroll
      for (int t = 0; t < 4; ++t)
        #pragma unroll
        for (int c = 0; c < 2; ++c) av[t][c] = (f32x4){0.f, 0.f, 0.f, 0.f};
      const bf16_t* wv = wqkvT + (size_t)(512 + 32 * h) * 256;
      #pragma unroll
      for (int ks = 0; ks < 8; ++ks) {
        bf16x8 aks[4];
        #pragma unroll
        for (int t = 0; t < 4; ++t) {
          int row = 32 * (t >> 1) + 4 * (t & 1) + rb;
          aks[t] = *(const bf16x8*)(smem + row * 512 + ((64 * ks + 16 * g) ^ SWZ(row)));
        }
        #pragma unroll
        for (int c = 0; c < 2; ++c) {
          bf16x8 fv = *(const bf16x8*)&wv[(16 * c + cc) * 256 + 32 * ks + 8 * g];
          #pragma unroll
          for (int t = 0; t < 4; ++t)
            av[t][c] = __builtin_amdgcn_mfma_f32_16x16x32_bf16(aks[t], fv, av[t][c], 0, 0, 0);
        }
      }
      #pragma unroll
      for (int c = 0; c < 2; ++c) {
        float bv = b_qkv[512 + 32 * h + 16 * c + cc];
        f32x4 bv4 = (f32x4){bv, bv, bv, bv};
        #pragma unroll
        for (int ks = 0; ks < 2; ++ks)
          vp[c][ks] = pack2(av[2 * ks][c] + bv4, av[2 * ks + 1][c] + bv4);
      }
    }
  };

  // ---- attention head h: per-qt fused softmax+PV, O written through to LDS ----
  auto attn = [&](int h, const bf16x8 qp[4], const bf16x8 kp[4],
                  const bf16x8 vp[2][2], bool toSlab) {
    const bf16_t* bI = biasI + h * 4096 + lane * 4;
    char* slab = smem + SLAB_OFF + (h >> 1) * SLAB_STRIDE;
    #pragma unroll
    for (int qt = 0; qt < 4; ++qt) {
      f32x4 sv[4];
      #pragma unroll
      for (int nt = 0; nt < 4; ++nt)
        sv[nt] = __builtin_amdgcn_mfma_f32_16x16x32_bf16(
            kp[nt], qp[qt], (f32x4){0.f, 0.f, 0.f, 0.f}, 0, 0, 0);
      #pragma unroll
      for (int nt = 0; nt < 4; ++nt) {
        bool dead = (maskY && ((qt < 2) != (nt < 2))) || (maskX && ((qt & 1) != (nt & 1)));
        if (dead) {
          sv[nt] = (f32x4){-3.0e38f, -3.0e38f, -3.0e38f, -3.0e38f};
        } else {
          bf16x4 bb4 = *(const bf16x4*)&bI[(qt * 4 + nt) * 256];
          sv[nt] = sv[nt] + __builtin_convertvector(bb4, f32x4);
        }
      }
      float mx = -3.0e38f;
      #pragma unroll
      for (int nt = 0; nt < 4; ++nt)
        #pragma unroll
        for (int i = 0; i < 4; ++i) mx = fmaxf(mx, sv[nt][i]);
      mx = fmaxf(mx, __shfl_xor(mx, 16));
      mx = fmaxf(mx, __shfl_xor(mx, 32));
      float sum = 0.f;
      #pragma unroll
      for (int nt = 0; nt < 4; ++nt)
        #pragma unroll
        for (int i = 0; i < 4; ++i) {
          float e = exp2f(sv[nt][i] - mx);
          sv[nt][i] = e;
          sum += e;
        }
      sum += __shfl_xor(sum, 16);
      sum += __shfl_xor(sum, 32);
      float rinv = 1.0f / sum;
      #pragma unroll
      for (int nt = 0; nt < 4; ++nt) sv[nt] *= rinv;
      bf16x8 p0 = pack2(sv[0], sv[1]);
      bf16x8 p1 = pack2(sv[2], sv[3]);
      int tok = 32 * (qt >> 1) + 4 * (qt & 1) + rb;
      #pragma unroll
      for (int c = 0; c < 2; ++c) {
        f32x4 oa = __builtin_amdgcn_mfma_f32_16x16x32_bf16(
            vp[c][0], p0, (f32x4){0.f, 0.f, 0.f, 0.f}, 0, 0, 0);
        oa = __builtin_amdgcn_mfma_f32_16x16x32_bf16(vp[c][1], p1, oa, 0, 0, 0);
        bf16x4 ob = __builtin_convertvector(oa, bf16x4);
        if (toSlab)
          *(bf16x4*)(slab + tok * 80 + 32 * c + 8 * g) = ob;
        else
          *(bf16x4*)(smem + tok * 512 + ((64 * h + 32 * c + 8 * g) ^ SWZ(tok))) = ob;
      }
    }
  };

  {
    bf16x8 qp[4], kp[4], vp[2][2];
    const int h0 = 2 * wave, h1 = 2 * wave + 1;
    qkv(h0, qp, kp, vp);
    attn(h0, qp, kp, vp, true);     // write-through to private even-head slab
    qkv(h1, qp, kp, vp);
    __syncthreads();                // all X reads complete -> X-overlay writable
    attn(h1, qp, kp, vp, false);    // write-through to X-overlay (odd channels)
  }
  __syncthreads();                  // all O visible

  // ---- out projection D = W_out·O^T + reverse-shift scatter ----
  // ks-step = head ks: even -> slab ks/2, odd -> X-overlay.
  {
    f32x4 pacc[4][4];  // wave owns 64 output channels: [c2][t]
    #pragma unroll
    for (int c = 0; c < 4; ++c)
      #pragma unroll
      for (int t = 0; t < 4; ++t) pacc[c][t] = (f32x4){0.f, 0.f, 0.f, 0.f};
    #pragma unroll
    for (int ks = 0; ks < 8; ++ks) {
      bf16x8 of[4];
      if ((ks & 1) == 0) {
        char* sb = smem + SLAB_OFF + (ks >> 1) * SLAB_STRIDE;
        #pragma unroll
        for (int t = 0; t < 4; ++t)
          of[t] = *(const bf16x8*)(sb + (16 * t + cc) * 80 + 16 * g);
      } else {
        #pragma unroll
        for (int t = 0; t < 4; ++t) {
          int row = 16 * t + cc;
          of[t] = *(const bf16x8*)(smem + row * 512 + ((64 * ks + 16 * g) ^ SWZ(row)));
        }
      }
      #pragma unroll
      for (int c2 = 0; c2 < 4; ++c2) {
        bf16x8 wf = *(const bf16x8*)&woutT[(size_t)(64 * wave + 16 * c2 + cc) * 256 + 32 * ks + 8 * g];
        #pragma unroll
        for (int t = 0; t < 4; ++t)
          pacc[c2][t] = __builtin_amdgcn_mfma_f32_16x16x32_bf16(wf, of[t], pacc[c2][t], 0, 0, 0);
      }
    }
    #pragma unroll
    for (int c2 = 0; c2 < 4; ++c2) {
      int ch = 64 * wave + 16 * c2 + 4 * g;
      float4 bo4 = *(const float4*)&b_out[ch];
      #pragma unroll
      for (int t = 0; t < 4; ++t) {
        int q = 16 * t + cc;
        int hh2 = (8 * wy + (q >> 3) + 4) & 63;
        int ww2 = (8 * wx + (q & 7) + 4) & 63;
        float4 st;
        st.x = pacc[c2][t][0] + bo4.x;
        st.y = pacc[c2][t][1] + bo4.y;
        st.z = pacc[c2][t][2] + bo4.z;
        st.w = pacc[c2][t][3] + bo4.w;
        *(float4*)&out[(((size_t)bb * 4096) + hh2 * 64 + ww2) * 256 + ch] = st;
      }
    }
  }
}

extern "C" void kernel_launch(void* const* d_in, const int* in_sizes, int n_in,
                              void* d_out, int out_size, void* d_ws, size_t ws_size,
                              hipStream_t stream) {
  const float* x       = (const float*)d_in[0];
  const float* w_qkv   = (const float*)d_in[1];
  const float* b_qkv   = (const float*)d_in[2];
  const float* w_out   = (const float*)d_in[3];
  const float* b_out   = (const float*)d_in[4];
  const float* pos_enc = (const float*)d_in[5];
  float* out = (float*)d_out;

  bf16_t* wqkvT = (bf16_t*)d_ws;          // 768*256
  bf16_t* woutT = wqkvT + 768 * 256;      // 256*256
  bf16_t* biasI = woutT + 256 * 256;      // 32768

  prep_weights<<<dim3(1024), dim3(256), 0, stream>>>(w_qkv, w_out, wqkvT, woutT);
  prep_bias<<<dim3(128), dim3(256), 0, stream>>>(pos_enc, biasI);
  swin_attn<<<dim3(2048), dim3(256), 0, stream>>>(
      x, b_qkv, b_out, wqkvT, woutT, biasI, out);
}

// Round 10
// 274.920 us; speedup vs baseline: 1.4666x; 1.3194x over previous
//
#include <hip/hip_runtime.h>

typedef __bf16 bf16_t;
typedef __bf16 bf16x4 __attribute__((ext_vector_type(4)));
typedef __bf16 bf16x8 __attribute__((ext_vector_type(8)));
typedef float f32x4 __attribute__((ext_vector_type(4)));

#define SCALE_LOG2E 0.25510803519787995f  // 32^-0.5 * log2(e)
#define LOG2E 1.4426950408889634f
#define SWZ(row) (((row) & 15) << 4)

__device__ __forceinline__ f32x4 mk4(float4 v) { return (f32x4){v.x, v.y, v.z, v.w}; }
__device__ __forceinline__ bf16x8 pack2(f32x4 a, f32x4 b) {
  bf16x4 lo = __builtin_convertvector(a, bf16x4);
  bf16x4 hi = __builtin_convertvector(b, bf16x4);
  return __builtin_shufflevector(lo, hi, 0, 1, 2, 3, 4, 5, 6, 7);
}

// ---- prep 1: transposed bf16 weights; Q/K head-rows permuted, Q pre-scaled ----
__global__ __launch_bounds__(256, 1) void prep_weights(
    const float* __restrict__ wqkv, const float* __restrict__ wout,
    bf16_t* __restrict__ wqkvT, bf16_t* __restrict__ woutT) {
  int i = blockIdx.x * 256 + threadIdx.x;   // 1024*256
  int n = i >> 8, k = i & 255;
  if (n < 768) {
    int s = n >> 8, hl = n & 255;
    int src;
    if (s < 2) {
      int h = hl >> 5, w = hl & 31, c = (w >> 4) & 1, r = w & 15;
      src = 32 * h + 8 * (r >> 2) + 4 * c + (r & 3);
    } else {
      src = hl;
    }
    float v = wqkv[k * 768 + s * 256 + src];
    if (s == 0) v *= SCALE_LOG2E;
    wqkvT[n * 256 + k] = (bf16_t)v;
  } else {
    int m = n - 768;
    woutT[m * 256 + k] = (bf16_t)wout[k * 256 + m];
  }
}

// ---- prep 2: rel-pos bias, interleaved fragment order, log2e-scaled ----
__global__ __launch_bounds__(256, 1) void prep_bias(
    const float* __restrict__ pos_enc, bf16_t* __restrict__ biasI) {
  int i = blockIdx.x * 256 + threadIdx.x;   // 8*4*4*64*4 = 32768
  int ii = i & 3, lane = (i >> 2) & 63, nt = (i >> 8) & 3, qt = (i >> 10) & 3, h = i >> 12;
  int g = lane >> 4, cc = lane & 15;
  int q = 32 * (qt >> 1) + 4 * (qt & 1) + 8 * (cc >> 2) + (cc & 3);
  int key = 32 * (nt >> 1) + 4 * (nt & 1) + 8 * g + ii;
  int qy = q >> 3, qx = q & 7, ky = key >> 3, kx = key & 7;
  biasI[i] = (bf16_t)(pos_enc[h * 225 + (qy - ky + 7) * 15 + (qx - kx + 7)] * LOG2E);
}

// LDS 32768 B, single region: X bf16 [64 tok][512B ch] -> O overlay after barrier.
// 256 threads = 4 waves, wave w owns heads 2w,2w+1.
// __launch_bounds__(256,2): 128-arch-reg cap (known spill-free); HW occupancy
// then resource-limited: 128 VGPR -> 16 waves/CU, LDS 32KB -> 4+ blocks/CU.
__global__ __launch_bounds__(256, 2) void swin_attn(
    const float* __restrict__ x,
    const float* __restrict__ b_qkv,
    const float* __restrict__ b_out,
    const bf16_t* __restrict__ wqkvT,
    const bf16_t* __restrict__ woutT,
    const bf16_t* __restrict__ biasI,
    float* __restrict__ out) {
  __shared__ __attribute__((aligned(16))) char smem[32768];

  const int tid  = threadIdx.x;
  const int wid  = blockIdx.x;
  const int bb   = wid >> 6;
  const int w64  = wid & 63;
  const int wy   = w64 >> 3, wx = w64 & 7;
  const int wave = tid >> 6, lane = tid & 63;
  const int g    = lane >> 4, cc = lane & 15;
  const bool maskY = (wy == 7), maskX = (wx == 7);
  const int rb = 8 * (cc >> 2) + (cc & 3);   // interleaved row base per lane

  // ---------------- phase 0: shifted-window gather -> X (bf16) ----------------
  {
    const float* xb = x + (size_t)bb * 4096 * 256;
    #pragma unroll
    for (int it = 0; it < 16; ++it) {
      int fi = tid + 256 * it;
      int r = fi >> 6, c4 = fi & 63;
      int hh = (8 * wy + (r >> 3) + 4) & 63;
      int ww = (8 * wx + (r & 7) + 4) & 63;
      const float4 v = ((const float4*)(xb + ((size_t)hh * 64 + ww) * 256))[c4];
      bf16x4 pk = __builtin_convertvector(mk4(v), bf16x4);
      *(bf16x4*)(smem + r * 512 + ((8 * c4) ^ SWZ(r))) = pk;
    }
  }
  __syncthreads();

  // ---- QKV for head h (QK pass then V pass; outputs are MFMA fragments) ----
  auto qkv = [&](int h, bf16x8 qp[4], bf16x8 kp[4], bf16x8 vp[2][2]) {
    {
      f32x4 aq[2][4], ak[2][4];
      #pragma unroll
      for (int c = 0; c < 2; ++c)
        #pragma unroll
        for (int t = 0; t < 4; ++t) {
          aq[c][t] = (f32x4){0.f, 0.f, 0.f, 0.f};
          ak[c][t] = (f32x4){0.f, 0.f, 0.f, 0.f};
        }
      const bf16_t* wq = wqkvT + (size_t)(32 * h) * 256;
      const bf16_t* wk = wqkvT + (size_t)(256 + 32 * h) * 256;
      #pragma unroll
      for (int ks = 0; ks < 8; ++ks) {
        bf16x8 aks[4];
        #pragma unroll
        for (int t = 0; t < 4; ++t) {
          int row = 32 * (t >> 1) + 4 * (t & 1) + rb;
          aks[t] = *(const bf16x8*)(smem + row * 512 + ((64 * ks + 16 * g) ^ SWZ(row)));
        }
        #pragma unroll
        for (int c = 0; c < 2; ++c) {
          int ro = (16 * c + cc) * 256 + 32 * ks + 8 * g;
          bf16x8 fq = *(const bf16x8*)&wq[ro];
          bf16x8 fk = *(const bf16x8*)&wk[ro];
          #pragma unroll
          for (int t = 0; t < 4; ++t) {
            aq[c][t] = __builtin_amdgcn_mfma_f32_16x16x32_bf16(fq, aks[t], aq[c][t], 0, 0, 0);
            ak[c][t] = __builtin_amdgcn_mfma_f32_16x16x32_bf16(fk, aks[t], ak[c][t], 0, 0, 0);
          }
        }
      }
      f32x4 bq0 = mk4(*(const float4*)&b_qkv[32 * h + 8 * g]) * SCALE_LOG2E;
      f32x4 bq1 = mk4(*(const float4*)&b_qkv[32 * h + 8 * g + 4]) * SCALE_LOG2E;
      f32x4 bk0 = mk4(*(const float4*)&b_qkv[256 + 32 * h + 8 * g]);
      f32x4 bk1 = mk4(*(const float4*)&b_qkv[256 + 32 * h + 8 * g + 4]);
      #pragma unroll
      for (int t = 0; t < 4; ++t) {
        qp[t] = pack2(aq[0][t] + bq0, aq[1][t] + bq1);
        kp[t] = pack2(ak[0][t] + bk0, ak[1][t] + bk1);
      }
    }
    {
      f32x4 av[4][2];
      #pragma unroll
      for (int t = 0; t < 4; ++t)
        #pragma unroll
        for (int c = 0; c < 2; ++c) av[t][c] = (f32x4){0.f, 0.f, 0.f, 0.f};
      const bf16_t* wv = wqkvT + (size_t)(512 + 32 * h) * 256;
      #pragma unroll
      for (int ks = 0; ks < 8; ++ks) {
        bf16x8 aks[4];
        #pragma unroll
        for (int t = 0; t < 4; ++t) {
          int row = 32 * (t >> 1) + 4 * (t & 1) + rb;
          aks[t] = *(const bf16x8*)(smem + row * 512 + ((64 * ks + 16 * g) ^ SWZ(row)));
        }
        #pragma unroll
        for (int c = 0; c < 2; ++c) {
          bf16x8 fv = *(const bf16x8*)&wv[(16 * c + cc) * 256 + 32 * ks + 8 * g];
          #pragma unroll
          for (int t = 0; t < 4; ++t)
            av[t][c] = __builtin_amdgcn_mfma_f32_16x16x32_bf16(aks[t], fv, av[t][c], 0, 0, 0);
        }
      }
      #pragma unroll
      for (int c = 0; c < 2; ++c) {
        float bv = b_qkv[512 + 32 * h + 16 * c + cc];
        f32x4 bv4 = (f32x4){bv, bv, bv, bv};
        #pragma unroll
        for (int ks = 0; ks < 2; ++ks)
          vp[c][ks] = pack2(av[2 * ks][c] + bv4, av[2 * ks + 1][c] + bv4);
      }
    }
  };

  // ---- attention head h: per-qt fused softmax+PV ----
  // toReg=true: pack O into ob (carried); else write through to X-overlay.
  auto attn = [&](int h, const bf16x8 qp[4], const bf16x8 kp[4],
                  const bf16x8 vp[2][2], bool toReg, bf16x4 ob[2][4]) {
    const bf16_t* bI = biasI + h * 4096 + lane * 4;
    #pragma unroll
    for (int qt = 0; qt < 4; ++qt) {
      f32x4 sv[4];
      #pragma unroll
      for (int nt = 0; nt < 4; ++nt)
        sv[nt] = __builtin_amdgcn_mfma_f32_16x16x32_bf16(
            kp[nt], qp[qt], (f32x4){0.f, 0.f, 0.f, 0.f}, 0, 0, 0);
      #pragma unroll
      for (int nt = 0; nt < 4; ++nt) {
        bool dead = (maskY && ((qt < 2) != (nt < 2))) || (maskX && ((qt & 1) != (nt & 1)));
        if (dead) {
          sv[nt] = (f32x4){-3.0e38f, -3.0e38f, -3.0e38f, -3.0e38f};
        } else {
          bf16x4 bb4 = *(const bf16x4*)&bI[(qt * 4 + nt) * 256];
          sv[nt] = sv[nt] + __builtin_convertvector(bb4, f32x4);
        }
      }
      float mx = -3.0e38f;
      #pragma unroll
      for (int nt = 0; nt < 4; ++nt)
        #pragma unroll
        for (int i = 0; i < 4; ++i) mx = fmaxf(mx, sv[nt][i]);
      mx = fmaxf(mx, __shfl_xor(mx, 16));
      mx = fmaxf(mx, __shfl_xor(mx, 32));
      float sum = 0.f;
      #pragma unroll
      for (int nt = 0; nt < 4; ++nt)
        #pragma unroll
        for (int i = 0; i < 4; ++i) {
          float e = exp2f(sv[nt][i] - mx);
          sv[nt][i] = e;
          sum += e;
        }
      sum += __shfl_xor(sum, 16);
      sum += __shfl_xor(sum, 32);
      float rinv = 1.0f / sum;
      #pragma unroll
      for (int nt = 0; nt < 4; ++nt) sv[nt] *= rinv;
      bf16x8 p0 = pack2(sv[0], sv[1]);
      bf16x8 p1 = pack2(sv[2], sv[3]);
      int tok = 32 * (qt >> 1) + 4 * (qt & 1) + rb;
      #pragma unroll
      for (int c = 0; c < 2; ++c) {
        f32x4 oa = __builtin_amdgcn_mfma_f32_16x16x32_bf16(
            vp[c][0], p0, (f32x4){0.f, 0.f, 0.f, 0.f}, 0, 0, 0);
        oa = __builtin_amdgcn_mfma_f32_16x16x32_bf16(vp[c][1], p1, oa, 0, 0, 0);
        bf16x4 o4 = __builtin_convertvector(oa, bf16x4);
        if (toReg)
          ob[c][qt] = o4;
        else
          *(bf16x4*)(smem + tok * 512 + ((64 * h + 32 * c + 8 * g) ^ SWZ(tok))) = o4;
      }
    }
  };

  {
    bf16x8 qp[4], kp[4], vp[2][2];
    bf16x4 ob0[2][4];
    const int h0 = 2 * wave, h1 = 2 * wave + 1;
    qkv(h0, qp, kp, vp);
    attn(h0, qp, kp, vp, true, ob0);   // O_h0 held in 16 regs
    qkv(h1, qp, kp, vp);
    __syncthreads();                   // all X reads complete -> overlay writable
    #pragma unroll
    for (int c = 0; c < 2; ++c)        // flush O_h0
      #pragma unroll
      for (int qt = 0; qt < 4; ++qt) {
        int tok = 32 * (qt >> 1) + 4 * (qt & 1) + rb;
        *(bf16x4*)(smem + tok * 512 + ((64 * h0 + 32 * c + 8 * g) ^ SWZ(tok))) = ob0[c][qt];
      }
    attn(h1, qp, kp, vp, false, ob0);  // O_h1 written through
  }
  __syncthreads();                     // O complete

  // ---- out projection D = W_out·O^T + reverse-shift scatter ----
  {
    f32x4 pacc[4][4];  // wave owns 64 output channels: [c2][t]
    #pragma unroll
    for (int c = 0; c < 4; ++c)
      #pragma unroll
      for (int t = 0; t < 4; ++t) pacc[c][t] = (f32x4){0.f, 0.f, 0.f, 0.f};
    #pragma unroll
    for (int ks = 0; ks < 8; ++ks) {
      bf16x8 of[4];
      #pragma unroll
      for (int t = 0; t < 4; ++t) {
        int row = 16 * t + cc;
        of[t] = *(const bf16x8*)(smem + row * 512 + ((64 * ks + 16 * g) ^ SWZ(row)));
      }
      #pragma unroll
      for (int c2 = 0; c2 < 4; ++c2) {
        bf16x8 wf = *(const bf16x8*)&woutT[(size_t)(64 * wave + 16 * c2 + cc) * 256 + 32 * ks + 8 * g];
        #pragma unroll
        for (int t = 0; t < 4; ++t)
          pacc[c2][t] = __builtin_amdgcn_mfma_f32_16x16x32_bf16(wf, of[t], pacc[c2][t], 0, 0, 0);
      }
    }
    #pragma unroll
    for (int c2 = 0; c2 < 4; ++c2) {
      int ch = 64 * wave + 16 * c2 + 4 * g;
      float4 bo4 = *(const float4*)&b_out[ch];
      #pragma unroll
      for (int t = 0; t < 4; ++t) {
        int q = 16 * t + cc;
        int hh2 = (8 * wy + (q >> 3) + 4) & 63;
        int ww2 = (8 * wx + (q & 7) + 4) & 63;
        float4 st;
        st.x = pacc[c2][t][0] + bo4.x;
        st.y = pacc[c2][t][1] + bo4.y;
        st.z = pacc[c2][t][2] + bo4.z;
        st.w = pacc[c2][t][3] + bo4.w;
        *(float4*)&out[(((size_t)bb * 4096) + hh2 * 64 + ww2) * 256 + ch] = st;
      }
    }
  }
}

extern "C" void kernel_launch(void* const* d_in, const int* in_sizes, int n_in,
                              void* d_out, int out_size, void* d_ws, size_t ws_size,
                              hipStream_t stream) {
  const float* x       = (const float*)d_in[0];
  const float* w_qkv   = (const float*)d_in[1];
  const float* b_qkv   = (const float*)d_in[2];
  const float* w_out   = (const float*)d_in[3];
  const float* b_out   = (const float*)d_in[4];
  const float* pos_enc = (const float*)d_in[5];
  float* out = (float*)d_out;

  bf16_t* wqkvT = (bf16_t*)d_ws;          // 768*256
  bf16_t* woutT = wqkvT + 768 * 256;      // 256*256
  bf16_t* biasI = woutT + 256 * 256;      // 32768

  prep_weights<<<dim3(1024), dim3(256), 0, stream>>>(w_qkv, w_out, wqkvT, woutT);
  prep_bias<<<dim3(128), dim3(256), 0, stream>>>(pos_enc, biasI);
  swin_attn<<<dim3(2048), dim3(256), 0, stream>>>(
      x, b_qkv, b_out, wqkvT, woutT, biasI, out);
}

// Round 11
// 256.209 us; speedup vs baseline: 1.5737x; 1.0730x over previous
//
#include <hip/hip_runtime.h>

typedef __bf16 bf16_t;
typedef __bf16 bf16x4 __attribute__((ext_vector_type(4)));
typedef __bf16 bf16x8 __attribute__((ext_vector_type(8)));
typedef float f32x4 __attribute__((ext_vector_type(4)));

#define SCALE_LOG2E 0.25510803519787995f  // 32^-0.5 * log2(e)
#define LOG2E 1.4426950408889634f
#define SWZ(row) (((row) & 15) << 4)
#define SLAB_OFF 32768
#define SLAB_STRIDE 5120   // per even-head slab: 64 tok x 80 B

__device__ __forceinline__ f32x4 mk4(float4 v) { return (f32x4){v.x, v.y, v.z, v.w}; }
__device__ __forceinline__ bf16x8 pack2(f32x4 a, f32x4 b) {
  bf16x4 lo = __builtin_convertvector(a, bf16x4);
  bf16x4 hi = __builtin_convertvector(b, bf16x4);
  return __builtin_shufflevector(lo, hi, 0, 1, 2, 3, 4, 5, 6, 7);
}

// ---- prep 1: transposed bf16 weights; Q/K head-rows permuted, Q pre-scaled ----
__global__ __launch_bounds__(256, 1) void prep_weights(
    const float* __restrict__ wqkv, const float* __restrict__ wout,
    bf16_t* __restrict__ wqkvT, bf16_t* __restrict__ woutT) {
  int i = blockIdx.x * 256 + threadIdx.x;   // 1024*256
  int n = i >> 8, k = i & 255;
  if (n < 768) {
    int s = n >> 8, hl = n & 255;
    int src;
    if (s < 2) {
      int h = hl >> 5, w = hl & 31, c = (w >> 4) & 1, r = w & 15;
      src = 32 * h + 8 * (r >> 2) + 4 * c + (r & 3);
    } else {
      src = hl;
    }
    float v = wqkv[k * 768 + s * 256 + src];
    if (s == 0) v *= SCALE_LOG2E;
    wqkvT[n * 256 + k] = (bf16_t)v;
  } else {
    int m = n - 768;
    woutT[m * 256 + k] = (bf16_t)wout[k * 256 + m];
  }
}

// ---- prep 2: rel-pos bias, interleaved fragment order, log2e-scaled ----
__global__ __launch_bounds__(256, 1) void prep_bias(
    const float* __restrict__ pos_enc, bf16_t* __restrict__ biasI) {
  int i = blockIdx.x * 256 + threadIdx.x;   // 8*4*4*64*4 = 32768
  int ii = i & 3, lane = (i >> 2) & 63, nt = (i >> 8) & 3, qt = (i >> 10) & 3, h = i >> 12;
  int g = lane >> 4, cc = lane & 15;
  int q = 32 * (qt >> 1) + 4 * (qt & 1) + 8 * (cc >> 2) + (cc & 3);
  int key = 32 * (nt >> 1) + 4 * (nt & 1) + 8 * g + ii;
  int qy = q >> 3, qx = q & 7, ky = key >> 3, kx = key & 7;
  biasI[i] = (bf16_t)(pos_enc[h * 225 + (qy - ky + 7) * 15 + (qx - kx + 7)] * LOG2E);
}

// LDS 53248 B -> 3 blocks/CU at (256,2):
//  [0, 32768): X bf16 [64 tok][512B ch] swz  -> odd-head O overlay after bar2
//  [32768, 53248): even-head O slabs: slab w (head 2w): [64 tok][80B]
// 256 threads = 4 waves, wave w owns heads 2w (even) and 2w+1 (odd).
// ZERO register carries across qkv() calls (the proven spill trigger at cap 128).
__global__ __launch_bounds__(256, 2) void swin_attn(
    const float* __restrict__ x,
    const float* __restrict__ b_qkv,
    const float* __restrict__ b_out,
    const bf16_t* __restrict__ wqkvT,
    const bf16_t* __restrict__ woutT,
    const bf16_t* __restrict__ biasI,
    float* __restrict__ out) {
  __shared__ __attribute__((aligned(16))) char smem[53248];

  const int tid  = threadIdx.x;
  const int wid  = blockIdx.x;
  const int bb   = wid >> 6;
  const int w64  = wid & 63;
  const int wy   = w64 >> 3, wx = w64 & 7;
  const int wave = tid >> 6, lane = tid & 63;
  const int g    = lane >> 4, cc = lane & 15;
  const bool maskY = (wy == 7), maskX = (wx == 7);
  const int rb = 8 * (cc >> 2) + (cc & 3);   // interleaved row base per lane

  // ---------------- phase 0: shifted-window gather -> X (bf16) ----------------
  {
    const float* xb = x + (size_t)bb * 4096 * 256;
    #pragma unroll
    for (int it = 0; it < 16; ++it) {
      int fi = tid + 256 * it;
      int r = fi >> 6, c4 = fi & 63;
      int hh = (8 * wy + (r >> 3) + 4) & 63;
      int ww = (8 * wx + (r & 7) + 4) & 63;
      const float4 v = ((const float4*)(xb + ((size_t)hh * 64 + ww) * 256))[c4];
      bf16x4 pk = __builtin_convertvector(mk4(v), bf16x4);
      *(bf16x4*)(smem + r * 512 + ((8 * c4) ^ SWZ(r))) = pk;
    }
  }
  __syncthreads();

  // ---- QKV for head h (QK pass then V pass; outputs are MFMA fragments) ----
  auto qkv = [&](int h, bf16x8 qp[4], bf16x8 kp[4], bf16x8 vp[2][2]) {
    {
      f32x4 aq[2][4], ak[2][4];
      #pragma unroll
      for (int c = 0; c < 2; ++c)
        #pragma unroll
        for (int t = 0; t < 4; ++t) {
          aq[c][t] = (f32x4){0.f, 0.f, 0.f, 0.f};
          ak[c][t] = (f32x4){0.f, 0.f, 0.f, 0.f};
        }
      const bf16_t* wq = wqkvT + (size_t)(32 * h) * 256;
      const bf16_t* wk = wqkvT + (size_t)(256 + 32 * h) * 256;
      #pragma unroll
      for (int ks = 0; ks < 8; ++ks) {
        bf16x8 aks[4];
        #pragma unroll
        for (int t = 0; t < 4; ++t) {
          int row = 32 * (t >> 1) + 4 * (t & 1) + rb;
          aks[t] = *(const bf16x8*)(smem + row * 512 + ((64 * ks + 16 * g) ^ SWZ(row)));
        }
        #pragma unroll
        for (int c = 0; c < 2; ++c) {
          int ro = (16 * c + cc) * 256 + 32 * ks + 8 * g;
          bf16x8 fq = *(const bf16x8*)&wq[ro];
          bf16x8 fk = *(const bf16x8*)&wk[ro];
          #pragma unroll
          for (int t = 0; t < 4; ++t) {
            aq[c][t] = __builtin_amdgcn_mfma_f32_16x16x32_bf16(fq, aks[t], aq[c][t], 0, 0, 0);
            ak[c][t] = __builtin_amdgcn_mfma_f32_16x16x32_bf16(fk, aks[t], ak[c][t], 0, 0, 0);
          }
        }
      }
      f32x4 bq0 = mk4(*(const float4*)&b_qkv[32 * h + 8 * g]) * SCALE_LOG2E;
      f32x4 bq1 = mk4(*(const float4*)&b_qkv[32 * h + 8 * g + 4]) * SCALE_LOG2E;
      f32x4 bk0 = mk4(*(const float4*)&b_qkv[256 + 32 * h + 8 * g]);
      f32x4 bk1 = mk4(*(const float4*)&b_qkv[256 + 32 * h + 8 * g + 4]);
      #pragma unroll
      for (int t = 0; t < 4; ++t) {
        qp[t] = pack2(aq[0][t] + bq0, aq[1][t] + bq1);
        kp[t] = pack2(ak[0][t] + bk0, ak[1][t] + bk1);
      }
    }
    {
      f32x4 av[4][2];
      #pragma unroll
      for (int t = 0; t < 4; ++t)
        #pragma unroll
        for (int c = 0; c < 2; ++c) av[t][c] = (f32x4){0.f, 0.f, 0.f, 0.f};
      const bf16_t* wv = wqkvT + (size_t)(512 + 32 * h) * 256;
      #pragma unroll
      for (int ks = 0; ks < 8; ++ks) {
        bf16x8 aks[4];
        #pragma unroll
        for (int t = 0; t < 4; ++t) {
          int row = 32 * (t >> 1) + 4 * (t & 1) + rb;
          aks[t] = *(const bf16x8*)(smem + row * 512 + ((64 * ks + 16 * g) ^ SWZ(row)));
        }
        #pragma unroll
        for (int c = 0; c < 2; ++c) {
          bf16x8 fv = *(const bf16x8*)&wv[(16 * c + cc) * 256 + 32 * ks + 8 * g];
          #pragma unroll
          for (int t = 0; t < 4; ++t)
            av[t][c] = __builtin_amdgcn_mfma_f32_16x16x32_bf16(aks[t], fv, av[t][c], 0, 0, 0);
        }
      }
      #pragma unroll
      for (int c = 0; c < 2; ++c) {
        float bv = b_qkv[512 + 32 * h + 16 * c + cc];
        f32x4 bv4 = (f32x4){bv, bv, bv, bv};
        #pragma unroll
        for (int ks = 0; ks < 2; ++ks)
          vp[c][ks] = pack2(av[2 * ks][c] + bv4, av[2 * ks + 1][c] + bv4);
      }
    }
  };

  // ---- attention head h: per-qt fused softmax+PV, O written through to LDS ----
  auto attn = [&](int h, const bf16x8 qp[4], const bf16x8 kp[4],
                  const bf16x8 vp[2][2], bool toSlab) {
    const bf16_t* bI = biasI + h * 4096 + lane * 4;
    char* slab = smem + SLAB_OFF + (h >> 1) * SLAB_STRIDE;
    #pragma unroll
    for (int qt = 0; qt < 4; ++qt) {
      f32x4 sv[4];
      #pragma unroll
      for (int nt = 0; nt < 4; ++nt)
        sv[nt] = __builtin_amdgcn_mfma_f32_16x16x32_bf16(
            kp[nt], qp[qt], (f32x4){0.f, 0.f, 0.f, 0.f}, 0, 0, 0);
      #pragma unroll
      for (int nt = 0; nt < 4; ++nt) {
        bool dead = (maskY && ((qt < 2) != (nt < 2))) || (maskX && ((qt & 1) != (nt & 1)));
        if (dead) {
          sv[nt] = (f32x4){-3.0e38f, -3.0e38f, -3.0e38f, -3.0e38f};
        } else {
          bf16x4 bb4 = *(const bf16x4*)&bI[(qt * 4 + nt) * 256];
          sv[nt] = sv[nt] + __builtin_convertvector(bb4, f32x4);
        }
      }
      float mx = -3.0e38f;
      #pragma unroll
      for (int nt = 0; nt < 4; ++nt)
        #pragma unroll
        for (int i = 0; i < 4; ++i) mx = fmaxf(mx, sv[nt][i]);
      mx = fmaxf(mx, __shfl_xor(mx, 16));
      mx = fmaxf(mx, __shfl_xor(mx, 32));
      float sum = 0.f;
      #pragma unroll
      for (int nt = 0; nt < 4; ++nt)
        #pragma unroll
        for (int i = 0; i < 4; ++i) {
          float e = exp2f(sv[nt][i] - mx);
          sv[nt][i] = e;
          sum += e;
        }
      sum += __shfl_xor(sum, 16);
      sum += __shfl_xor(sum, 32);
      float rinv = 1.0f / sum;
      #pragma unroll
      for (int nt = 0; nt < 4; ++nt) sv[nt] *= rinv;
      bf16x8 p0 = pack2(sv[0], sv[1]);
      bf16x8 p1 = pack2(sv[2], sv[3]);
      int tok = 32 * (qt >> 1) + 4 * (qt & 1) + rb;
      #pragma unroll
      for (int c = 0; c < 2; ++c) {
        f32x4 oa = __builtin_amdgcn_mfma_f32_16x16x32_bf16(
            vp[c][0], p0, (f32x4){0.f, 0.f, 0.f, 0.f}, 0, 0, 0);
        oa = __builtin_amdgcn_mfma_f32_16x16x32_bf16(vp[c][1], p1, oa, 0, 0, 0);
        bf16x4 ob = __builtin_convertvector(oa, bf16x4);
        if (toSlab)
          *(bf16x4*)(slab + tok * 80 + 32 * c + 8 * g) = ob;
        else
          *(bf16x4*)(smem + tok * 512 + ((64 * h + 32 * c + 8 * g) ^ SWZ(tok))) = ob;
      }
    }
  };

  {
    bf16x8 qp[4], kp[4], vp[2][2];
    const int h0 = 2 * wave, h1 = 2 * wave + 1;
    qkv(h0, qp, kp, vp);
    attn(h0, qp, kp, vp, true);     // write-through to private even-head slab
    qkv(h1, qp, kp, vp);
    __syncthreads();                // all X reads complete -> X-overlay writable
    attn(h1, qp, kp, vp, false);    // write-through to X-overlay (odd channels)
  }
  __syncthreads();                  // all O visible

  // ---- out projection D = W_out·O^T + reverse-shift scatter ----
  // ks-step = head ks: even -> slab ks/2, odd -> X-overlay.
  {
    f32x4 pacc[4][4];  // wave owns 64 output channels: [c2][t]
    #pragma unroll
    for (int c = 0; c < 4; ++c)
      #pragma unroll
      for (int t = 0; t < 4; ++t) pacc[c][t] = (f32x4){0.f, 0.f, 0.f, 0.f};
    #pragma unroll
    for (int ks = 0; ks < 8; ++ks) {
      bf16x8 of[4];
      if ((ks & 1) == 0) {
        char* sb = smem + SLAB_OFF + (ks >> 1) * SLAB_STRIDE;
        #pragma unroll
        for (int t = 0; t < 4; ++t)
          of[t] = *(const bf16x8*)(sb + (16 * t + cc) * 80 + 16 * g);
      } else {
        #pragma unroll
        for (int t = 0; t < 4; ++t) {
          int row = 16 * t + cc;
          of[t] = *(const bf16x8*)(smem + row * 512 + ((64 * ks + 16 * g) ^ SWZ(row)));
        }
      }
      #pragma unroll
      for (int c2 = 0; c2 < 4; ++c2) {
        bf16x8 wf = *(const bf16x8*)&woutT[(size_t)(64 * wave + 16 * c2 + cc) * 256 + 32 * ks + 8 * g];
        #pragma unroll
        for (int t = 0; t < 4; ++t)
          pacc[c2][t] = __builtin_amdgcn_mfma_f32_16x16x32_bf16(wf, of[t], pacc[c2][t], 0, 0, 0);
      }
    }
    #pragma unroll
    for (int c2 = 0; c2 < 4; ++c2) {
      int ch = 64 * wave + 16 * c2 + 4 * g;
      float4 bo4 = *(const float4*)&b_out[ch];
      #pragma unroll
      for (int t = 0; t < 4; ++t) {
        int q = 16 * t + cc;
        int hh2 = (8 * wy + (q >> 3) + 4) & 63;
        int ww2 = (8 * wx + (q & 7) + 4) & 63;
        float4 st;
        st.x = pacc[c2][t][0] + bo4.x;
        st.y = pacc[c2][t][1] + bo4.y;
        st.z = pacc[c2][t][2] + bo4.z;
        st.w = pacc[c2][t][3] + bo4.w;
        *(float4*)&out[(((size_t)bb * 4096) + hh2 * 64 + ww2) * 256 + ch] = st;
      }
    }
  }
}

extern "C" void kernel_launch(void* const* d_in, const int* in_sizes, int n_in,
                              void* d_out, int out_size, void* d_ws, size_t ws_size,
                              hipStream_t stream) {
  const float* x       = (const float*)d_in[0];
  const float* w_qkv   = (const float*)d_in[1];
  const float* b_qkv   = (const float*)d_in[2];
  const float* w_out   = (const float*)d_in[3];
  const float* b_out   = (const float*)d_in[4];
  const float* pos_enc = (const float*)d_in[5];
  float* out = (float*)d_out;

  bf16_t* wqkvT = (bf16_t*)d_ws;          // 768*256
  bf16_t* woutT = wqkvT + 768 * 256;      // 256*256
  bf16_t* biasI = woutT + 256 * 256;      // 32768

  prep_weights<<<dim3(1024), dim3(256), 0, stream>>>(w_qkv, w_out, wqkvT, woutT);
  prep_bias<<<dim3(128), dim3(256), 0, stream>>>(pos_enc, biasI);
  swin_attn<<<dim3(2048), dim3(256), 0, stream>>>(
      x, b_qkv, b_out, wqkvT, woutT, biasI, out);
}

// Round 12
// 229.419 us; speedup vs baseline: 1.7575x; 1.1168x over previous
//
#include <hip/hip_runtime.h>

typedef __bf16 bf16_t;
typedef __bf16 bf16x4 __attribute__((ext_vector_type(4)));
typedef __bf16 bf16x8 __attribute__((ext_vector_type(8)));
typedef float f32x4 __attribute__((ext_vector_type(4)));

#define SCALE_LOG2E 0.25510803519787995f  // 32^-0.5 * log2(e)
#define LOG2E 1.4426950408889634f
#define SWZ(row) (((row) & 15) << 4)

__device__ __forceinline__ f32x4 mk4(float4 v) { return (f32x4){v.x, v.y, v.z, v.w}; }
__device__ __forceinline__ bf16x8 pack2(f32x4 a, f32x4 b) {
  bf16x4 lo = __builtin_convertvector(a, bf16x4);
  bf16x4 hi = __builtin_convertvector(b, bf16x4);
  return __builtin_shufflevector(lo, hi, 0, 1, 2, 3, 4, 5, 6, 7);
}

// ---- prep 1: transposed bf16 weights; Q/K head-rows permuted, Q pre-scaled ----
__global__ __launch_bounds__(256, 1) void prep_weights(
    const float* __restrict__ wqkv, const float* __restrict__ wout,
    bf16_t* __restrict__ wqkvT, bf16_t* __restrict__ woutT) {
  int i = blockIdx.x * 256 + threadIdx.x;   // 1024*256
  int n = i >> 8, k = i & 255;
  if (n < 768) {
    int s = n >> 8, hl = n & 255;
    int src;
    if (s < 2) {
      int h = hl >> 5, w = hl & 31, c = (w >> 4) & 1, r = w & 15;
      src = 32 * h + 8 * (r >> 2) + 4 * c + (r & 3);
    } else {
      src = hl;
    }
    float v = wqkv[k * 768 + s * 256 + src];
    if (s == 0) v *= SCALE_LOG2E;
    wqkvT[n * 256 + k] = (bf16_t)v;
  } else {
    int m = n - 768;
    woutT[m * 256 + k] = (bf16_t)wout[k * 256 + m];
  }
}

// ---- prep 2: rel-pos bias, interleaved fragment order, log2e-scaled ----
__global__ __launch_bounds__(256, 1) void prep_bias(
    const float* __restrict__ pos_enc, bf16_t* __restrict__ biasI) {
  int i = blockIdx.x * 256 + threadIdx.x;   // 8*4*4*64*4 = 32768
  int ii = i & 3, lane = (i >> 2) & 63, nt = (i >> 8) & 3, qt = (i >> 10) & 3, h = i >> 12;
  int g = lane >> 4, cc = lane & 15;
  int q = 32 * (qt >> 1) + 4 * (qt & 1) + 8 * (cc >> 2) + (cc & 3);
  int key = 32 * (nt >> 1) + 4 * (nt & 1) + 8 * g + ii;
  int qy = q >> 3, qx = q & 7, ky = key >> 3, kx = key & 7;
  biasI[i] = (bf16_t)(pos_enc[h * 225 + (qy - ky + 7) * 15 + (qx - kx + 7)] * LOG2E);
}

// LDS 32768 B, single region: X bf16 [64 tok][512B ch] -> O overlay after barrier.
// 512 threads = 8 waves, wave == head. (512,2): arch cap 128; per-pass live
// registers held to ~60-95 so ~35 regs of load-pipelining headroom remain.
__global__ __launch_bounds__(512, 2) void swin_attn(
    const float* __restrict__ x,
    const float* __restrict__ b_qkv,
    const float* __restrict__ b_out,
    const bf16_t* __restrict__ wqkvT,
    const bf16_t* __restrict__ woutT,
    const bf16_t* __restrict__ biasI,
    float* __restrict__ out) {
  __shared__ __attribute__((aligned(16))) char smem[32768];

  const int tid  = threadIdx.x;
  const int wid  = blockIdx.x;
  const int bb   = wid >> 6;
  const int w64  = wid & 63;
  const int wy   = w64 >> 3, wx = w64 & 7;
  const int h    = tid >> 6;                 // wave index == head index
  const int lane = tid & 63;
  const int g    = lane >> 4, cc = lane & 15;
  const bool maskY = (wy == 7), maskX = (wx == 7);
  const int rb = 8 * (cc >> 2) + (cc & 3);   // interleaved row base per lane

  // ---------------- phase 0: shifted-window gather -> X (bf16) ----------------
  {
    const float* xb = x + (size_t)bb * 4096 * 256;
    #pragma unroll
    for (int it = 0; it < 8; ++it) {
      int fi = tid + 512 * it;
      int r = fi >> 6, c4 = fi & 63;
      int hh = (8 * wy + (r >> 3) + 4) & 63;
      int ww = (8 * wx + (r & 7) + 4) & 63;
      const float4 v = ((const float4*)(xb + ((size_t)hh * 64 + ww) * 256))[c4];
      bf16x4 pk = __builtin_convertvector(mk4(v), bf16x4);
      *(bf16x4*)(smem + r * 512 + ((8 * c4) ^ SWZ(r))) = pk;
    }
  }
  __syncthreads();

  bf16x8 qp[4], kp[4], vp[2][2];

  // ---------------- Q pass (one 32-reg accumulator block live) ----------------
  {
    f32x4 aq[2][4];
    #pragma unroll
    for (int c = 0; c < 2; ++c)
      #pragma unroll
      for (int t = 0; t < 4; ++t) aq[c][t] = (f32x4){0.f, 0.f, 0.f, 0.f};
    const bf16_t* wq = wqkvT + (size_t)(32 * h) * 256;
    #pragma unroll
    for (int ks = 0; ks < 8; ++ks) {
      bf16x8 aks[4];
      #pragma unroll
      for (int t = 0; t < 4; ++t) {
        int row = 32 * (t >> 1) + 4 * (t & 1) + rb;
        aks[t] = *(const bf16x8*)(smem + row * 512 + ((64 * ks + 16 * g) ^ SWZ(row)));
      }
      #pragma unroll
      for (int c = 0; c < 2; ++c) {
        bf16x8 fq = *(const bf16x8*)&wq[(16 * c + cc) * 256 + 32 * ks + 8 * g];
        #pragma unroll
        for (int t = 0; t < 4; ++t)
          aq[c][t] = __builtin_amdgcn_mfma_f32_16x16x32_bf16(fq, aks[t], aq[c][t], 0, 0, 0);
      }
    }
    f32x4 bq0 = mk4(*(const float4*)&b_qkv[32 * h + 8 * g]) * SCALE_LOG2E;
    f32x4 bq1 = mk4(*(const float4*)&b_qkv[32 * h + 8 * g + 4]) * SCALE_LOG2E;
    #pragma unroll
    for (int t = 0; t < 4; ++t) qp[t] = pack2(aq[0][t] + bq0, aq[1][t] + bq1);
  }
  __builtin_amdgcn_sched_barrier(0);   // keep passes separate (pressure isolation)

  // ---------------- K pass ----------------
  {
    f32x4 ak[2][4];
    #pragma unroll
    for (int c = 0; c < 2; ++c)
      #pragma unroll
      for (int t = 0; t < 4; ++t) ak[c][t] = (f32x4){0.f, 0.f, 0.f, 0.f};
    const bf16_t* wk = wqkvT + (size_t)(256 + 32 * h) * 256;
    #pragma unroll
    for (int ks = 0; ks < 8; ++ks) {
      bf16x8 aks[4];
      #pragma unroll
      for (int t = 0; t < 4; ++t) {
        int row = 32 * (t >> 1) + 4 * (t & 1) + rb;
        aks[t] = *(const bf16x8*)(smem + row * 512 + ((64 * ks + 16 * g) ^ SWZ(row)));
      }
      #pragma unroll
      for (int c = 0; c < 2; ++c) {
        bf16x8 fk = *(const bf16x8*)&wk[(16 * c + cc) * 256 + 32 * ks + 8 * g];
        #pragma unroll
        for (int t = 0; t < 4; ++t)
          ak[c][t] = __builtin_amdgcn_mfma_f32_16x16x32_bf16(fk, aks[t], ak[c][t], 0, 0, 0);
      }
    }
    f32x4 bk0 = mk4(*(const float4*)&b_qkv[256 + 32 * h + 8 * g]);
    f32x4 bk1 = mk4(*(const float4*)&b_qkv[256 + 32 * h + 8 * g + 4]);
    #pragma unroll
    for (int t = 0; t < 4; ++t) kp[t] = pack2(ak[0][t] + bk0, ak[1][t] + bk1);
  }
  __builtin_amdgcn_sched_barrier(0);

  // ---------------- V pass ----------------
  {
    f32x4 av[4][2];
    #pragma unroll
    for (int t = 0; t < 4; ++t)
      #pragma unroll
      for (int c = 0; c < 2; ++c) av[t][c] = (f32x4){0.f, 0.f, 0.f, 0.f};
    const bf16_t* wv = wqkvT + (size_t)(512 + 32 * h) * 256;
    #pragma unroll
    for (int ks = 0; ks < 8; ++ks) {
      bf16x8 aks[4];
      #pragma unroll
      for (int t = 0; t < 4; ++t) {
        int row = 32 * (t >> 1) + 4 * (t & 1) + rb;
        aks[t] = *(const bf16x8*)(smem + row * 512 + ((64 * ks + 16 * g) ^ SWZ(row)));
      }
      #pragma unroll
      for (int c = 0; c < 2; ++c) {
        bf16x8 fv = *(const bf16x8*)&wv[(16 * c + cc) * 256 + 32 * ks + 8 * g];
        #pragma unroll
        for (int t = 0; t < 4; ++t)
          av[t][c] = __builtin_amdgcn_mfma_f32_16x16x32_bf16(aks[t], fv, av[t][c], 0, 0, 0);
      }
    }
    #pragma unroll
    for (int c = 0; c < 2; ++c) {
      float bv = b_qkv[512 + 32 * h + 16 * c + cc];
      f32x4 bv4 = (f32x4){bv, bv, bv, bv};
      #pragma unroll
      for (int ks = 0; ks < 2; ++ks)
        vp[c][ks] = pack2(av[2 * ks][c] + bv4, av[2 * ks + 1][c] + bv4);
    }
  }
  __syncthreads();  // all X reads complete -> O may overlay X

  // ---------------- attention (per-qt fused), O write-through to overlay ----------------
  {
    const bf16_t* bI = biasI + h * 4096 + lane * 4;
    #pragma unroll
    for (int qt = 0; qt < 4; ++qt) {
      f32x4 sv[4];
      #pragma unroll
      for (int nt = 0; nt < 4; ++nt)
        sv[nt] = __builtin_amdgcn_mfma_f32_16x16x32_bf16(
            kp[nt], qp[qt], (f32x4){0.f, 0.f, 0.f, 0.f}, 0, 0, 0);
      #pragma unroll
      for (int nt = 0; nt < 4; ++nt) {
        bool dead = (maskY && ((qt < 2) != (nt < 2))) || (maskX && ((qt & 1) != (nt & 1)));
        if (dead) {
          sv[nt] = (f32x4){-3.0e38f, -3.0e38f, -3.0e38f, -3.0e38f};
        } else {
          bf16x4 bb4 = *(const bf16x4*)&bI[(qt * 4 + nt) * 256];
          sv[nt] = sv[nt] + __builtin_convertvector(bb4, f32x4);
        }
      }
      float mx = -3.0e38f;
      #pragma unroll
      for (int nt = 0; nt < 4; ++nt)
        #pragma unroll
        for (int i = 0; i < 4; ++i) mx = fmaxf(mx, sv[nt][i]);
      mx = fmaxf(mx, __shfl_xor(mx, 16));
      mx = fmaxf(mx, __shfl_xor(mx, 32));
      float sum = 0.f;
      #pragma unroll
      for (int nt = 0; nt < 4; ++nt)
        #pragma unroll
        for (int i = 0; i < 4; ++i) {
          float e = exp2f(sv[nt][i] - mx);
          sv[nt][i] = e;
          sum += e;
        }
      sum += __shfl_xor(sum, 16);
      sum += __shfl_xor(sum, 32);
      float rinv = 1.0f / sum;
      #pragma unroll
      for (int nt = 0; nt < 4; ++nt) sv[nt] *= rinv;
      bf16x8 p0 = pack2(sv[0], sv[1]);
      bf16x8 p1 = pack2(sv[2], sv[3]);
      int tok = 32 * (qt >> 1) + 4 * (qt & 1) + rb;
      #pragma unroll
      for (int c = 0; c < 2; ++c) {
        f32x4 oa = __builtin_amdgcn_mfma_f32_16x16x32_bf16(
            vp[c][0], p0, (f32x4){0.f, 0.f, 0.f, 0.f}, 0, 0, 0);
        oa = __builtin_amdgcn_mfma_f32_16x16x32_bf16(vp[c][1], p1, oa, 0, 0, 0);
        bf16x4 o4 = __builtin_convertvector(oa, bf16x4);
        *(bf16x4*)(smem + tok * 512 + ((64 * h + 32 * c + 8 * g) ^ SWZ(tok))) = o4;
      }
    }
  }
  __syncthreads();  // O complete

  // ---------------- out projection D = W_out·O^T + reverse-shift scatter ----------------
  {
    f32x4 pacc[2][4];  // wave owns 32 output channels: [c2][t]
    #pragma unroll
    for (int c = 0; c < 2; ++c)
      #pragma unroll
      for (int t = 0; t < 4; ++t) pacc[c][t] = (f32x4){0.f, 0.f, 0.f, 0.f};
    #pragma unroll
    for (int ks = 0; ks < 8; ++ks) {
      bf16x8 of[4];
      #pragma unroll
      for (int t = 0; t < 4; ++t) {
        int row = 16 * t + cc;
        of[t] = *(const bf16x8*)(smem + row * 512 + ((64 * ks + 16 * g) ^ SWZ(row)));
      }
      #pragma unroll
      for (int c2 = 0; c2 < 2; ++c2) {
        bf16x8 wf = *(const bf16x8*)&woutT[(size_t)(32 * h + 16 * c2 + cc) * 256 + 32 * ks + 8 * g];
        #pragma unroll
        for (int t = 0; t < 4; ++t)
          pacc[c2][t] = __builtin_amdgcn_mfma_f32_16x16x32_bf16(wf, of[t], pacc[c2][t], 0, 0, 0);
      }
    }
    #pragma unroll
    for (int c2 = 0; c2 < 2; ++c2) {
      int ch = 32 * h + 16 * c2 + 4 * g;
      float4 bo4 = *(const float4*)&b_out[ch];
      #pragma unroll
      for (int t = 0; t < 4; ++t) {
        int q = 16 * t + cc;
        int hh2 = (8 * wy + (q >> 3) + 4) & 63;
        int ww2 = (8 * wx + (q & 7) + 4) & 63;
        float4 st;
        st.x = pacc[c2][t][0] + bo4.x;
        st.y = pacc[c2][t][1] + bo4.y;
        st.z = pacc[c2][t][2] + bo4.z;
        st.w = pacc[c2][t][3] + bo4.w;
        *(float4*)&out[(((size_t)bb * 4096) + hh2 * 64 + ww2) * 256 + ch] = st;
      }
    }
  }
}

extern "C" void kernel_launch(void* const* d_in, const int* in_sizes, int n_in,
                              void* d_out, int out_size, void* d_ws, size_t ws_size,
                              hipStream_t stream) {
  const float* x       = (const float*)d_in[0];
  const float* w_qkv   = (const float*)d_in[1];
  const float* b_qkv   = (const float*)d_in[2];
  const float* w_out   = (const float*)d_in[3];
  const float* b_out   = (const float*)d_in[4];
  const float* pos_enc = (const float*)d_in[5];
  float* out = (float*)d_out;

  bf16_t* wqkvT = (bf16_t*)d_ws;          // 768*256
  bf16_t* woutT = wqkvT + 768 * 256;      // 256*256
  bf16_t* biasI = woutT + 256 * 256;      // 32768

  prep_weights<<<dim3(1024), dim3(256), 0, stream>>>(w_qkv, w_out, wqkvT, woutT);
  prep_bias<<<dim3(128), dim3(256), 0, stream>>>(pos_enc, biasI);
  swin_attn<<<dim3(2048), dim3(512), 0, stream>>>(
      x, b_qkv, b_out, wqkvT, woutT, biasI, out);
}

// Round 13
// 215.383 us; speedup vs baseline: 1.8720x; 1.0652x over previous
//
#include <hip/hip_runtime.h>

typedef __bf16 bf16_t;
typedef __bf16 bf16x4 __attribute__((ext_vector_type(4)));
typedef __bf16 bf16x8 __attribute__((ext_vector_type(8)));
typedef float f32x4 __attribute__((ext_vector_type(4)));

#define SCALE_LOG2E 0.25510803519787995f  // 32^-0.5 * log2(e)
#define LOG2E 1.4426950408889634f
#define SWZ(row) (((row) & 15) << 4)
#define SLAB_OFF 32768
#define SLAB_STRIDE 5120   // per even-head slab: 64 tok x 80 B

__device__ __forceinline__ f32x4 mk4(float4 v) { return (f32x4){v.x, v.y, v.z, v.w}; }
__device__ __forceinline__ bf16x8 pack2(f32x4 a, f32x4 b) {
  bf16x4 lo = __builtin_convertvector(a, bf16x4);
  bf16x4 hi = __builtin_convertvector(b, bf16x4);
  return __builtin_shufflevector(lo, hi, 0, 1, 2, 3, 4, 5, 6, 7);
}

// ---- prep 1: transposed bf16 weights; Q/K head-rows permuted, Q pre-scaled ----
__global__ __launch_bounds__(256, 1) void prep_weights(
    const float* __restrict__ wqkv, const float* __restrict__ wout,
    bf16_t* __restrict__ wqkvT, bf16_t* __restrict__ woutT) {
  int i = blockIdx.x * 256 + threadIdx.x;   // 1024*256
  int n = i >> 8, k = i & 255;
  if (n < 768) {
    int s = n >> 8, hl = n & 255;
    int src;
    if (s < 2) {
      int h = hl >> 5, w = hl & 31, c = (w >> 4) & 1, r = w & 15;
      src = 32 * h + 8 * (r >> 2) + 4 * c + (r & 3);
    } else {
      src = hl;
    }
    float v = wqkv[k * 768 + s * 256 + src];
    if (s == 0) v *= SCALE_LOG2E;
    wqkvT[n * 256 + k] = (bf16_t)v;
  } else {
    int m = n - 768;
    woutT[m * 256 + k] = (bf16_t)wout[k * 256 + m];
  }
}

// ---- prep 2: rel-pos bias, interleaved fragment order, log2e-scaled ----
__global__ __launch_bounds__(256, 1) void prep_bias(
    const float* __restrict__ pos_enc, bf16_t* __restrict__ biasI) {
  int i = blockIdx.x * 256 + threadIdx.x;   // 8*4*4*64*4 = 32768
  int ii = i & 3, lane = (i >> 2) & 63, nt = (i >> 8) & 3, qt = (i >> 10) & 3, h = i >> 12;
  int g = lane >> 4, cc = lane & 15;
  int q = 32 * (qt >> 1) + 4 * (qt & 1) + 8 * (cc >> 2) + (cc & 3);
  int key = 32 * (nt >> 1) + 4 * (nt & 1) + 8 * g + ii;
  int qy = q >> 3, qx = q & 7, ky = key >> 3, kx = key & 7;
  biasI[i] = (bf16_t)(pos_enc[h * 225 + (qy - ky + 7) * 15 + (qx - kx + 7)] * LOG2E);
}

// LDS 53248 B -> 3 blocks/CU:
//  [0, 32768): X bf16 [64 tok][512B ch] swz  -> odd-head O overlay after bar2
//  [32768, 53248): even-head O slabs: slab w (head 2w): [64 tok][80B]
// 256 threads = 4 waves; wave w owns heads 2w, 2w+1. 3-pass Q/K/V (32-acc max,
// proven spill-free at 84 arch regs in round 12); zero carries across passes.
__global__ __launch_bounds__(256, 2) void swin_attn(
    const float* __restrict__ x,
    const float* __restrict__ b_qkv,
    const float* __restrict__ b_out,
    const bf16_t* __restrict__ wqkvT,
    const bf16_t* __restrict__ woutT,
    const bf16_t* __restrict__ biasI,
    float* __restrict__ out) {
  __shared__ __attribute__((aligned(16))) char smem[53248];

  const int tid  = threadIdx.x;
  const int wid  = blockIdx.x;
  const int bb   = wid >> 6;
  const int w64  = wid & 63;
  const int wy   = w64 >> 3, wx = w64 & 7;
  const int wave = tid >> 6, lane = tid & 63;
  const int g    = lane >> 4, cc = lane & 15;
  const bool maskY = (wy == 7), maskX = (wx == 7);
  const int rb = 8 * (cc >> 2) + (cc & 3);   // interleaved row base per lane

  // ---------------- phase 0: shifted-window gather -> X (bf16) ----------------
  {
    const float* xb = x + (size_t)bb * 4096 * 256;
    #pragma unroll
    for (int it = 0; it < 16; ++it) {
      int fi = tid + 256 * it;
      int r = fi >> 6, c4 = fi & 63;
      int hh = (8 * wy + (r >> 3) + 4) & 63;
      int ww = (8 * wx + (r & 7) + 4) & 63;
      const float4 v = ((const float4*)(xb + ((size_t)hh * 64 + ww) * 256))[c4];
      bf16x4 pk = __builtin_convertvector(mk4(v), bf16x4);
      *(bf16x4*)(smem + r * 512 + ((8 * c4) ^ SWZ(r))) = pk;
    }
  }
  __syncthreads();

  // ---- QKV for head h: three separate passes (Q, K, V), 32 acc regs live max ----
  auto qkv3 = [&](int h, bf16x8 qp[4], bf16x8 kp[4], bf16x8 vp[2][2]) {
    // Q pass
    {
      f32x4 aq[2][4];
      #pragma unroll
      for (int c = 0; c < 2; ++c)
        #pragma unroll
        for (int t = 0; t < 4; ++t) aq[c][t] = (f32x4){0.f, 0.f, 0.f, 0.f};
      const bf16_t* wq = wqkvT + (size_t)(32 * h) * 256;
      #pragma unroll
      for (int ks = 0; ks < 8; ++ks) {
        bf16x8 aks[4];
        #pragma unroll
        for (int t = 0; t < 4; ++t) {
          int row = 32 * (t >> 1) + 4 * (t & 1) + rb;
          aks[t] = *(const bf16x8*)(smem + row * 512 + ((64 * ks + 16 * g) ^ SWZ(row)));
        }
        #pragma unroll
        for (int c = 0; c < 2; ++c) {
          bf16x8 fq = *(const bf16x8*)&wq[(16 * c + cc) * 256 + 32 * ks + 8 * g];
          #pragma unroll
          for (int t = 0; t < 4; ++t)
            aq[c][t] = __builtin_amdgcn_mfma_f32_16x16x32_bf16(fq, aks[t], aq[c][t], 0, 0, 0);
        }
      }
      f32x4 bq0 = mk4(*(const float4*)&b_qkv[32 * h + 8 * g]) * SCALE_LOG2E;
      f32x4 bq1 = mk4(*(const float4*)&b_qkv[32 * h + 8 * g + 4]) * SCALE_LOG2E;
      #pragma unroll
      for (int t = 0; t < 4; ++t) qp[t] = pack2(aq[0][t] + bq0, aq[1][t] + bq1);
    }
    __builtin_amdgcn_sched_barrier(0);   // pressure isolation between passes
    // K pass
    {
      f32x4 ak[2][4];
      #pragma unroll
      for (int c = 0; c < 2; ++c)
        #pragma unroll
        for (int t = 0; t < 4; ++t) ak[c][t] = (f32x4){0.f, 0.f, 0.f, 0.f};
      const bf16_t* wk = wqkvT + (size_t)(256 + 32 * h) * 256;
      #pragma unroll
      for (int ks = 0; ks < 8; ++ks) {
        bf16x8 aks[4];
        #pragma unroll
        for (int t = 0; t < 4; ++t) {
          int row = 32 * (t >> 1) + 4 * (t & 1) + rb;
          aks[t] = *(const bf16x8*)(smem + row * 512 + ((64 * ks + 16 * g) ^ SWZ(row)));
        }
        #pragma unroll
        for (int c = 0; c < 2; ++c) {
          bf16x8 fk = *(const bf16x8*)&wk[(16 * c + cc) * 256 + 32 * ks + 8 * g];
          #pragma unroll
          for (int t = 0; t < 4; ++t)
            ak[c][t] = __builtin_amdgcn_mfma_f32_16x16x32_bf16(fk, aks[t], ak[c][t], 0, 0, 0);
        }
      }
      f32x4 bk0 = mk4(*(const float4*)&b_qkv[256 + 32 * h + 8 * g]);
      f32x4 bk1 = mk4(*(const float4*)&b_qkv[256 + 32 * h + 8 * g + 4]);
      #pragma unroll
      for (int t = 0; t < 4; ++t) kp[t] = pack2(ak[0][t] + bk0, ak[1][t] + bk1);
    }
    __builtin_amdgcn_sched_barrier(0);
    // V pass
    {
      f32x4 av[4][2];
      #pragma unroll
      for (int t = 0; t < 4; ++t)
        #pragma unroll
        for (int c = 0; c < 2; ++c) av[t][c] = (f32x4){0.f, 0.f, 0.f, 0.f};
      const bf16_t* wv = wqkvT + (size_t)(512 + 32 * h) * 256;
      #pragma unroll
      for (int ks = 0; ks < 8; ++ks) {
        bf16x8 aks[4];
        #pragma unroll
        for (int t = 0; t < 4; ++t) {
          int row = 32 * (t >> 1) + 4 * (t & 1) + rb;
          aks[t] = *(const bf16x8*)(smem + row * 512 + ((64 * ks + 16 * g) ^ SWZ(row)));
        }
        #pragma unroll
        for (int c = 0; c < 2; ++c) {
          bf16x8 fv = *(const bf16x8*)&wv[(16 * c + cc) * 256 + 32 * ks + 8 * g];
          #pragma unroll
          for (int t = 0; t < 4; ++t)
            av[t][c] = __builtin_amdgcn_mfma_f32_16x16x32_bf16(aks[t], fv, av[t][c], 0, 0, 0);
        }
      }
      #pragma unroll
      for (int c = 0; c < 2; ++c) {
        float bv = b_qkv[512 + 32 * h + 16 * c + cc];
        f32x4 bv4 = (f32x4){bv, bv, bv, bv};
        #pragma unroll
        for (int ks = 0; ks < 2; ++ks)
          vp[c][ks] = pack2(av[2 * ks][c] + bv4, av[2 * ks + 1][c] + bv4);
      }
    }
  };

  // ---- attention head h: per-qt fused softmax+PV, O written through to LDS ----
  auto attn = [&](int h, const bf16x8 qp[4], const bf16x8 kp[4],
                  const bf16x8 vp[2][2], bool toSlab) {
    const bf16_t* bI = biasI + h * 4096 + lane * 4;
    char* slab = smem + SLAB_OFF + (h >> 1) * SLAB_STRIDE;
    #pragma unroll
    for (int qt = 0; qt < 4; ++qt) {
      f32x4 sv[4];
      #pragma unroll
      for (int nt = 0; nt < 4; ++nt)
        sv[nt] = __builtin_amdgcn_mfma_f32_16x16x32_bf16(
            kp[nt], qp[qt], (f32x4){0.f, 0.f, 0.f, 0.f}, 0, 0, 0);
      #pragma unroll
      for (int nt = 0; nt < 4; ++nt) {
        bool dead = (maskY && ((qt < 2) != (nt < 2))) || (maskX && ((qt & 1) != (nt & 1)));
        if (dead) {
          sv[nt] = (f32x4){-3.0e38f, -3.0e38f, -3.0e38f, -3.0e38f};
        } else {
          bf16x4 bb4 = *(const bf16x4*)&bI[(qt * 4 + nt) * 256];
          sv[nt] = sv[nt] + __builtin_convertvector(bb4, f32x4);
        }
      }
      float mx = -3.0e38f;
      #pragma unroll
      for (int nt = 0; nt < 4; ++nt)
        #pragma unroll
        for (int i = 0; i < 4; ++i) mx = fmaxf(mx, sv[nt][i]);
      mx = fmaxf(mx, __shfl_xor(mx, 16));
      mx = fmaxf(mx, __shfl_xor(mx, 32));
      float sum = 0.f;
      #pragma unroll
      for (int nt = 0; nt < 4; ++nt)
        #pragma unroll
        for (int i = 0; i < 4; ++i) {
          float e = exp2f(sv[nt][i] - mx);
          sv[nt][i] = e;
          sum += e;
        }
      sum += __shfl_xor(sum, 16);
      sum += __shfl_xor(sum, 32);
      float rinv = 1.0f / sum;
      #pragma unroll
      for (int nt = 0; nt < 4; ++nt) sv[nt] *= rinv;
      bf16x8 p0 = pack2(sv[0], sv[1]);
      bf16x8 p1 = pack2(sv[2], sv[3]);
      int tok = 32 * (qt >> 1) + 4 * (qt & 1) + rb;
      #pragma unroll
      for (int c = 0; c < 2; ++c) {
        f32x4 oa = __builtin_amdgcn_mfma_f32_16x16x32_bf16(
            vp[c][0], p0, (f32x4){0.f, 0.f, 0.f, 0.f}, 0, 0, 0);
        oa = __builtin_amdgcn_mfma_f32_16x16x32_bf16(vp[c][1], p1, oa, 0, 0, 0);
        bf16x4 ob = __builtin_convertvector(oa, bf16x4);
        if (toSlab)
          *(bf16x4*)(slab + tok * 80 + 32 * c + 8 * g) = ob;
        else
          *(bf16x4*)(smem + tok * 512 + ((64 * h + 32 * c + 8 * g) ^ SWZ(tok))) = ob;
      }
    }
  };

  {
    bf16x8 qp[4], kp[4], vp[2][2];
    const int h0 = 2 * wave, h1 = 2 * wave + 1;
    qkv3(h0, qp, kp, vp);
    attn(h0, qp, kp, vp, true);     // write-through to private even-head slab
    qkv3(h1, qp, kp, vp);
    __syncthreads();                // all X reads complete -> X-overlay writable
    attn(h1, qp, kp, vp, false);    // write-through to X-overlay (odd channels)
  }
  __syncthreads();                  // all O visible

  // ---- out projection D = W_out·O^T + reverse-shift scatter ----
  // ks-step = head ks: even -> slab ks/2, odd -> X-overlay.
  {
    f32x4 pacc[4][4];  // wave owns 64 output channels: [c2][t]
    #pragma unroll
    for (int c = 0; c < 4; ++c)
      #pragma unroll
      for (int t = 0; t < 4; ++t) pacc[c][t] = (f32x4){0.f, 0.f, 0.f, 0.f};
    #pragma unroll
    for (int ks = 0; ks < 8; ++ks) {
      bf16x8 of[4];
      if ((ks & 1) == 0) {
        char* sb = smem + SLAB_OFF + (ks >> 1) * SLAB_STRIDE;
        #pragma unroll
        for (int t = 0; t < 4; ++t)
          of[t] = *(const bf16x8*)(sb + (16 * t + cc) * 80 + 16 * g);
      } else {
        #pragma unroll
        for (int t = 0; t < 4; ++t) {
          int row = 16 * t + cc;
          of[t] = *(const bf16x8*)(smem + row * 512 + ((64 * ks + 16 * g) ^ SWZ(row)));
        }
      }
      #pragma unroll
      for (int c2 = 0; c2 < 4; ++c2) {
        bf16x8 wf = *(const bf16x8*)&woutT[(size_t)(64 * wave + 16 * c2 + cc) * 256 + 32 * ks + 8 * g];
        #pragma unroll
        for (int t = 0; t < 4; ++t)
          pacc[c2][t] = __builtin_amdgcn_mfma_f32_16x16x32_bf16(wf, of[t], pacc[c2][t], 0, 0, 0);
      }
    }
    #pragma unroll
    for (int c2 = 0; c2 < 4; ++c2) {
      int ch = 64 * wave + 16 * c2 + 4 * g;
      float4 bo4 = *(const float4*)&b_out[ch];
      #pragma unroll
      for (int t = 0; t < 4; ++t) {
        int q = 16 * t + cc;
        int hh2 = (8 * wy + (q >> 3) + 4) & 63;
        int ww2 = (8 * wx + (q & 7) + 4) & 63;
        float4 st;
        st.x = pacc[c2][t][0] + bo4.x;
        st.y = pacc[c2][t][1] + bo4.y;
        st.z = pacc[c2][t][2] + bo4.z;
        st.w = pacc[c2][t][3] + bo4.w;
        *(float4*)&out[(((size_t)bb * 4096) + hh2 * 64 + ww2) * 256 + ch] = st;
      }
    }
  }
}

extern "C" void kernel_launch(void* const* d_in, const int* in_sizes, int n_in,
                              void* d_out, int out_size, void* d_ws, size_t ws_size,
                              hipStream_t stream) {
  const float* x       = (const float*)d_in[0];
  const float* w_qkv   = (const float*)d_in[1];
  const float* b_qkv   = (const float*)d_in[2];
  const float* w_out   = (const float*)d_in[3];
  const float* b_out   = (const float*)d_in[4];
  const float* pos_enc = (const float*)d_in[5];
  float* out = (float*)d_out;

  bf16_t* wqkvT = (bf16_t*)d_ws;          // 768*256
  bf16_t* woutT = wqkvT + 768 * 256;      // 256*256
  bf16_t* biasI = woutT + 256 * 256;      // 32768

  prep_weights<<<dim3(1024), dim3(256), 0, stream>>>(w_qkv, w_out, wqkvT, woutT);
  prep_bias<<<dim3(128), dim3(256), 0, stream>>>(pos_enc, biasI);
  swin_attn<<<dim3(2048), dim3(256), 0, stream>>>(
      x, b_qkv, b_out, wqkvT, woutT, biasI, out);
}